// Round 6
// baseline (1089.313 us; speedup 1.0000x reference)
//
#include <hip/hip_runtime.h>
#include <hip/hip_bf16.h>

#define N_NODES 50000
#define N_EDGES 800000
#define IN_DIM  256
#define OUT_DIM 64
#define NCH     49    // ceil(50000/1024) scan chunks
#define NBKT    196   // ceil(50000/256) coarse buckets (dst>>8)

// ---------------------------------------------------------------------------
// probe: edge dtype (int64 vs int32). Values < 50000 -> if int64, every odd
// 32-bit word is 0 over the first 512 entries.
// ---------------------------------------------------------------------------
__global__ void probe_kernel(const unsigned int* __restrict__ e, int* __restrict__ flag) {
    __shared__ int nz;
    if (threadIdx.x == 0) nz = 0;
    __syncthreads();
    if (e[2 * threadIdx.x + 1] != 0u) nz = 1;
    __syncthreads();
    if (threadIdx.x == 0) flag[0] = (nz == 0) ? 1 : 0;
}

__device__ __forceinline__ int load_idx(const void* edges, int is64, long long i) {
    if (is64) return (int)((const long long*)edges)[i];
    return ((const int*)edges)[i];
}

// Coarse bucket counts: bcnt[dst>>8]++
__global__ void degb_kernel(const void* __restrict__ edges, const int* __restrict__ flag,
                            int* __restrict__ bcnt) {
    int e = blockIdx.x * 256 + threadIdx.x;
    if (e >= N_EDGES) return;
    int is64 = flag[0];
    int d = load_idx(edges, is64, (long long)N_EDGES + e);
    atomicAdd(&bcnt[d >> 8], 1);
}

// Exclusive scan of 196 bucket counts -> bstart (and atomic cursors bcur)
__global__ void bscan_kernel(const int* __restrict__ bcnt, int* __restrict__ bstart,
                             int* __restrict__ bcur) {
    __shared__ int smem[256];
    int v = (threadIdx.x < NBKT) ? bcnt[threadIdx.x] : 0;
    smem[threadIdx.x] = v;
    __syncthreads();
    for (int s = 1; s < 256; s <<= 1) {
        int t = 0;
        if (threadIdx.x >= s) t = smem[threadIdx.x - s];
        __syncthreads();
        if (threadIdx.x >= s) smem[threadIdx.x] += t;
        __syncthreads();
    }
    if (threadIdx.x < NBKT) {
        int excl = smem[threadIdx.x] - v;
        bstart[threadIdx.x] = excl;
        bcur[threadIdx.x] = excl;
    }
    if (threadIdx.x == 0) bstart[NBKT] = N_EDGES;
}

// Pass A: append (src,dst) to coarse bucket (sequential write streams);
// also fine-grained degree count cnt[d]++.
__global__ void passA_kernel(const void* __restrict__ edges, const int* __restrict__ flag,
                             int* __restrict__ bcur, int2* __restrict__ ebuf,
                             int* __restrict__ cnt) {
    int e = blockIdx.x * 256 + threadIdx.x;
    if (e >= N_EDGES) return;
    int is64 = flag[0];
    int s = load_idx(edges, is64, e);
    int d = load_idx(edges, is64, (long long)N_EDGES + e);
    atomicAdd(&cnt[d], 1);
    int pos = atomicAdd(&bcur[d >> 8], 1);
    ebuf[pos] = make_int2(s, d);
}

// --------------------- hierarchical exclusive scan (off) -------------------
__global__ __launch_bounds__(1024) void scan_local(const int* __restrict__ cnt,
                                                   int* __restrict__ off,
                                                   int* __restrict__ partial,
                                                   float* __restrict__ dinv) {
    __shared__ int smem[1024];
    int i = blockIdx.x * 1024 + threadIdx.x;
    int v = (i < N_NODES) ? cnt[i] : 0;
    if (i < N_NODES) dinv[i] = rsqrtf((float)(v + 1));
    smem[threadIdx.x] = v;
    __syncthreads();
    for (int s = 1; s < 1024; s <<= 1) {
        int t = 0;
        if (threadIdx.x >= s) t = smem[threadIdx.x - s];
        __syncthreads();
        if (threadIdx.x >= s) smem[threadIdx.x] += t;
        __syncthreads();
    }
    int incl = smem[threadIdx.x];
    if (i < N_NODES) off[i] = incl - v;
    if (threadIdx.x == 1023) partial[blockIdx.x] = incl;
}

__global__ void scan_mid(int* __restrict__ partial) {
    int lane = threadIdx.x;
    int v = (lane < NCH) ? partial[lane] : 0;
    int orig = v;
    for (int s = 1; s < 64; s <<= 1) {
        int t = __shfl_up(v, s);
        if (lane >= s) v += t;
    }
    if (lane < NCH) partial[lane] = v - orig;
    if (lane == 63) partial[63] = v;
}

__global__ __launch_bounds__(1024) void scan_add(int* __restrict__ off,
                                                 const int* __restrict__ partial,
                                                 int* __restrict__ cursor) {
    int i = blockIdx.x * 1024 + threadIdx.x;
    if (i < N_NODES) {
        int o = off[i] + partial[blockIdx.x];
        off[i] = o;
        cursor[i] = o;
    }
    if (i == 0) off[N_NODES] = partial[63];
}

// Pass B: one block per coarse bucket; scatter to final CSR slots.
// All targets (cursor window 1 KB, csr window ~32 KB) stay cache-local.
__global__ __launch_bounds__(256) void passB_kernel(const int2* __restrict__ ebuf,
                                                    const int* __restrict__ bstart,
                                                    const float* __restrict__ dinv,
                                                    int* __restrict__ cursor,
                                                    int2* __restrict__ csr) {
    int beg = bstart[blockIdx.x];
    int end = bstart[blockIdx.x + 1];
    for (int i = beg + threadIdx.x; i < end; i += 256) {
        int2 e = ebuf[i];
        float norm = dinv[e.x] * dinv[e.y];
        int pos = atomicAdd(&cursor[e.y], 1);
        csr[pos] = make_int2(e.x, __float_as_int(norm));
    }
}

// ---------------------------------------------------------------------------
// H[N,64] = X[N,K] @ W[K,64].
// 128 threads (2 waves), BM=64 -> grid 782 (~3 blocks/CU). Thread
// (cg=lane&7, rg=lane>>3, wave) owns 4 rows x 8 cols. Per 4-k step:
// 4 global b128 (8-way lane broadcast), 8 LDS b128 (broadcast-dedup'd),
// 128 FMA -> VALU/L1/LDS balanced at ~10/10/8 us for layer 1.
// ---------------------------------------------------------------------------
template <int K>
__global__ __launch_bounds__(128) void gemm_kernel(const float* __restrict__ X,
                                                   const float* __restrict__ W,
                                                   float* __restrict__ H) {
    constexpr int KC = 64;
    __shared__ float wlds[KC][64];

    const int lane = threadIdx.x & 63;
    const int wave = threadIdx.x >> 6;
    const int cg = lane & 7;
    const int rg = lane >> 3;
    const int c0 = cg * 8;
    const int r0 = blockIdx.x * 64 + (wave * 8 + rg) * 4;

    const float* xrow[4];
#pragma unroll
    for (int i = 0; i < 4; ++i) {
        int r = r0 + i;
        if (r >= N_NODES) r = N_NODES - 1;   // clamp; stores guarded
        xrow[i] = X + (size_t)r * K;
    }

    float acc[4][8] = {};

    for (int kc = 0; kc < K; kc += KC) {
        __syncthreads();
        for (int idx = threadIdx.x; idx < KC * 16; idx += 128) {
            ((float4*)wlds)[idx] = ((const float4*)(W + kc * 64))[idx];
        }
        __syncthreads();

#pragma unroll 4
        for (int k = 0; k < KC; k += 4) {
            float4 a[4];
#pragma unroll
            for (int i = 0; i < 4; ++i) a[i] = *(const float4*)(xrow[i] + kc + k);
#pragma unroll
            for (int kk = 0; kk < 4; ++kk) {
                float4 w0 = *(const float4*)&wlds[k + kk][c0];
                float4 w1 = *(const float4*)&wlds[k + kk][c0 + 4];
#pragma unroll
                for (int i = 0; i < 4; ++i) {
                    float av = ((const float*)&a[i])[kk];
                    acc[i][0] = fmaf(av, w0.x, acc[i][0]);
                    acc[i][1] = fmaf(av, w0.y, acc[i][1]);
                    acc[i][2] = fmaf(av, w0.z, acc[i][2]);
                    acc[i][3] = fmaf(av, w0.w, acc[i][3]);
                    acc[i][4] = fmaf(av, w1.x, acc[i][4]);
                    acc[i][5] = fmaf(av, w1.y, acc[i][5]);
                    acc[i][6] = fmaf(av, w1.z, acc[i][6]);
                    acc[i][7] = fmaf(av, w1.w, acc[i][7]);
                }
            }
        }
    }

#pragma unroll
    for (int i = 0; i < 4; ++i) {
        int r = r0 + i;
        if (r < N_NODES) {
            *(float4*)&H[(size_t)r * 64 + c0]     = make_float4(acc[i][0], acc[i][1], acc[i][2], acc[i][3]);
            *(float4*)&H[(size_t)r * 64 + c0 + 4] = make_float4(acc[i][4], acc[i][5], acc[i][6], acc[i][7]);
        }
    }
}

// ---------------------------------------------------------------------------
// Gather-aggregate: one wave per dst node, lane = column. Edges in batches
// of 8: 8 independent H-row loads in flight, then 8 FMAs.
// ---------------------------------------------------------------------------
__global__ __launch_bounds__(256) void agg_csr(const float* __restrict__ H,
                                               const float* __restrict__ dinv,
                                               const float* __restrict__ b,
                                               const int* __restrict__ off,
                                               const int2* __restrict__ csr,
                                               float* __restrict__ out) {
    int wid  = (blockIdx.x * 256 + threadIdx.x) >> 6;
    int lane = threadIdx.x & 63;
    if (wid >= N_NODES) return;
    float dd = dinv[wid];
    float acc = H[(size_t)wid * 64 + lane] * dd * dd + b[lane];
    int beg = off[wid], end = off[wid + 1];
    for (int k0 = beg; k0 < end; k0 += 64) {
        int myk = k0 + lane;
        int2 ev = (myk < end) ? csr[myk] : make_int2(0, 0);
        int cnt = min(64, end - k0);
        int i = 0;
        for (; i + 8 <= cnt; i += 8) {
            float v[8], nm[8];
#pragma unroll
            for (int jj = 0; jj < 8; ++jj) {
                int s  = __shfl(ev.x, i + jj);
                nm[jj] = __shfl(__int_as_float(ev.y), i + jj);
                v[jj]  = H[(size_t)s * 64 + lane];
            }
#pragma unroll
            for (int jj = 0; jj < 8; ++jj) acc = fmaf(v[jj], nm[jj], acc);
        }
        for (; i < cnt; ++i) {
            int   s  = __shfl(ev.x, i);
            float nm = __shfl(__int_as_float(ev.y), i);
            acc = fmaf(H[(size_t)s * 64 + lane], nm, acc);
        }
    }
    out[(size_t)wid * 64 + lane] = fmaxf(acc, 0.f);
}

extern "C" void kernel_launch(void* const* d_in, const int* in_sizes, int n_in,
                              void* d_out, int out_size, void* d_ws, size_t ws_size,
                              hipStream_t stream) {
    const float* feat = (const float*)d_in[0];
    const float* W1   = (const float*)d_in[1];
    const float* b1   = (const float*)d_in[2];
    const float* W2   = (const float*)d_in[3];
    const float* b2   = (const float*)d_in[4];
    const void*  edges = d_in[5];
    float* out = (float*)d_out;

    char* ws = (char*)d_ws;
    int*   flag    = (int*)ws;                         // @0
    int*   bstart  = (int*)(ws + 256);                 // 197 ints
    int*   bcur    = (int*)(ws + 1280);                // 196 ints
    int*   partial = (int*)(ws + 2304);                // 64 ints
    int*   bcnt    = (int*)(ws + 4096);                // 256 ints  (memset region start)
    int*   cnt     = (int*)(ws + 4096 + 1024);         // 50000 ints (contiguous w/ bcnt)
    size_t o = 4096 + 1024 + 200704;
    float* dinv    = (float*)(ws + o); o += 200704;
    int*   off     = (int*)(ws + o);   o += 200704;    // 50001 ints
    int*   cursor  = (int*)(ws + o);   o += 200704;
    int2*  csr     = (int2*)(ws + o);  o += (size_t)N_EDGES * 8;   // 6.4 MB
    float* H       = (float*)(ws + o);                 // 12.8 MB
    int2*  ebuf    = (int2*)H;   // aliases H: dead before gemm1 writes H

    const int NB_E = (N_EDGES + 255) / 256;
    const int NB_G = (N_NODES + 63) / 64;
    const int NB_W = (N_NODES * 64 + 255) / 256;

    hipMemsetAsync(bcnt, 0, 1024 + 200704, stream);    // bcnt + cnt
    probe_kernel<<<1, 256, 0, stream>>>((const unsigned int*)edges, flag);
    degb_kernel<<<NB_E, 256, 0, stream>>>(edges, flag, bcnt);
    bscan_kernel<<<1, 256, 0, stream>>>(bcnt, bstart, bcur);
    passA_kernel<<<NB_E, 256, 0, stream>>>(edges, flag, bcur, ebuf, cnt);
    scan_local<<<NCH, 1024, 0, stream>>>(cnt, off, partial, dinv);
    scan_mid<<<1, 64, 0, stream>>>(partial);
    scan_add<<<NCH, 1024, 0, stream>>>(off, partial, cursor);
    passB_kernel<<<NBKT, 256, 0, stream>>>(ebuf, bstart, dinv, cursor, csr);

    // Layer 1
    gemm_kernel<IN_DIM><<<NB_G, 128, 0, stream>>>(feat, W1, H);
    agg_csr<<<NB_W, 256, 0, stream>>>(H, dinv, b1, off, csr, out);

    // Layer 2 (out holds relu'd z1)
    gemm_kernel<OUT_DIM><<<NB_G, 128, 0, stream>>>(out, W2, H);
    agg_csr<<<NB_W, 256, 0, stream>>>(H, dinv, b2, off, csr, out);
}

// Round 7
// 231.837 us; speedup vs baseline: 4.6986x; 4.6986x over previous
//
#include <hip/hip_runtime.h>
#include <hip/hip_bf16.h>

#define N_NODES 50000
#define N_EDGES 800000
#define IN_DIM  256
#define OUT_DIM 64
#define NCH     49    // ceil(50000/1024) scan chunks

// ---------------------------------------------------------------------------
// Inline edge-dtype probe (int64 vs int32). Block-local: 256 threads check
// the first 256 odd 32-bit words; for int64 values < 50000 all are zero.
// For int32 random data P(all zero) ~ (1/50000)^256 ~ 0.
// Call from a 256-thread block; returns wave-uniform is64.
// ---------------------------------------------------------------------------
__device__ __forceinline__ int probe_is64(const void* edges, int* nz_s) {
    if (threadIdx.x == 0) *nz_s = 0;
    __syncthreads();
    if (((const unsigned int*)edges)[2 * threadIdx.x + 1] != 0u) *nz_s = 1;
    __syncthreads();
    return (*nz_s == 0);
}

// cnt[dst]++ per edge (non-returning int atomics, 50K addresses)
__global__ void deg_count(const void* __restrict__ edges, int* __restrict__ cnt) {
    __shared__ int nz;
    int is64 = probe_is64(edges, &nz);
    int e = blockIdx.x * 256 + threadIdx.x;
    if (e >= N_EDGES) return;
    int d = is64 ? (int)((const long long*)edges)[(long long)N_EDGES + e]
                 : ((const int*)edges)[(long long)N_EDGES + e];
    atomicAdd(&cnt[d], 1);
}

// --------------------- hierarchical exclusive scan -------------------------
__global__ __launch_bounds__(1024) void scan_local(const int* __restrict__ cnt,
                                                   int* __restrict__ off,
                                                   int* __restrict__ partial,
                                                   float* __restrict__ dinv) {
    __shared__ int smem[1024];
    int i = blockIdx.x * 1024 + threadIdx.x;
    int v = (i < N_NODES) ? cnt[i] : 0;
    if (i < N_NODES) dinv[i] = rsqrtf((float)(v + 1));
    smem[threadIdx.x] = v;
    __syncthreads();
    for (int s = 1; s < 1024; s <<= 1) {
        int t = 0;
        if (threadIdx.x >= s) t = smem[threadIdx.x - s];
        __syncthreads();
        if (threadIdx.x >= s) smem[threadIdx.x] += t;
        __syncthreads();
    }
    int incl = smem[threadIdx.x];
    if (i < N_NODES) off[i] = incl - v;
    if (threadIdx.x == 1023) partial[blockIdx.x] = incl;
}

__global__ void scan_mid(int* __restrict__ partial) {
    int lane = threadIdx.x;
    int v = (lane < NCH) ? partial[lane] : 0;
    int orig = v;
    for (int s = 1; s < 64; s <<= 1) {
        int t = __shfl_up(v, s);
        if (lane >= s) v += t;
    }
    if (lane < NCH) partial[lane] = v - orig;
    if (lane == 63) partial[63] = v;
}

__global__ __launch_bounds__(1024) void scan_add(int* __restrict__ off,
                                                 const int* __restrict__ partial,
                                                 int* __restrict__ cursor) {
    int i = blockIdx.x * 1024 + threadIdx.x;
    if (i < N_NODES) {
        int o = off[i] + partial[blockIdx.x];
        off[i] = o;
        cursor[i] = o;
    }
    if (i == 0) off[N_NODES] = partial[63];
}

// Bucket edges by dst: csr_src[pos] = src. 50K cursor addresses -> ~16
// conflicts each (fine). 4B payload: norm recomputed in agg from dinv.
__global__ void scatter_kernel(const void* __restrict__ edges,
                               int* __restrict__ cursor,
                               int* __restrict__ csr_src) {
    __shared__ int nz;
    int is64 = probe_is64(edges, &nz);
    int e = blockIdx.x * 256 + threadIdx.x;
    if (e >= N_EDGES) return;
    int s, d;
    if (is64) {
        s = (int)((const long long*)edges)[e];
        d = (int)((const long long*)edges)[(long long)N_EDGES + e];
    } else {
        s = ((const int*)edges)[e];
        d = ((const int*)edges)[(long long)N_EDGES + e];
    }
    int pos = atomicAdd(&cursor[d], 1);
    csr_src[pos] = s;
}

// ---------------------------------------------------------------------------
// H[N,64] = X[N,K] @ W[K,64].
// 128 threads (2 waves), BM=64 -> grid 782 (~3 blocks/CU). Thread
// (cg=lane&7, rg=lane>>3, wave) owns 4 rows x 8 cols. Per 4-k step:
// 4 global b128 (8-way lane broadcast -> L1), 8 LDS b128, 128 FMA.
// ---------------------------------------------------------------------------
template <int K>
__global__ __launch_bounds__(128) void gemm_kernel(const float* __restrict__ X,
                                                   const float* __restrict__ W,
                                                   float* __restrict__ H) {
    constexpr int KC = 64;
    __shared__ float wlds[KC][64];

    const int lane = threadIdx.x & 63;
    const int wave = threadIdx.x >> 6;
    const int cg = lane & 7;
    const int rg = lane >> 3;
    const int c0 = cg * 8;
    const int r0 = blockIdx.x * 64 + (wave * 8 + rg) * 4;

    const float* xrow[4];
#pragma unroll
    for (int i = 0; i < 4; ++i) {
        int r = r0 + i;
        if (r >= N_NODES) r = N_NODES - 1;   // clamp; stores guarded
        xrow[i] = X + (size_t)r * K;
    }

    float acc[4][8] = {};

    for (int kc = 0; kc < K; kc += KC) {
        __syncthreads();
        for (int idx = threadIdx.x; idx < KC * 16; idx += 128) {
            ((float4*)wlds)[idx] = ((const float4*)(W + kc * 64))[idx];
        }
        __syncthreads();

#pragma unroll 4
        for (int k = 0; k < KC; k += 4) {
            float4 a[4];
#pragma unroll
            for (int i = 0; i < 4; ++i) a[i] = *(const float4*)(xrow[i] + kc + k);
#pragma unroll
            for (int kk = 0; kk < 4; ++kk) {
                float4 w0 = *(const float4*)&wlds[k + kk][c0];
                float4 w1 = *(const float4*)&wlds[k + kk][c0 + 4];
#pragma unroll
                for (int i = 0; i < 4; ++i) {
                    float av = ((const float*)&a[i])[kk];
                    acc[i][0] = fmaf(av, w0.x, acc[i][0]);
                    acc[i][1] = fmaf(av, w0.y, acc[i][1]);
                    acc[i][2] = fmaf(av, w0.z, acc[i][2]);
                    acc[i][3] = fmaf(av, w0.w, acc[i][3]);
                    acc[i][4] = fmaf(av, w1.x, acc[i][4]);
                    acc[i][5] = fmaf(av, w1.y, acc[i][5]);
                    acc[i][6] = fmaf(av, w1.z, acc[i][6]);
                    acc[i][7] = fmaf(av, w1.w, acc[i][7]);
                }
            }
        }
    }

#pragma unroll
    for (int i = 0; i < 4; ++i) {
        int r = r0 + i;
        if (r < N_NODES) {
            *(float4*)&H[(size_t)r * 64 + c0]     = make_float4(acc[i][0], acc[i][1], acc[i][2], acc[i][3]);
            *(float4*)&H[(size_t)r * 64 + c0 + 4] = make_float4(acc[i][4], acc[i][5], acc[i][6], acc[i][7]);
        }
    }
}

// ---------------------------------------------------------------------------
// Gather-aggregate: one wave per dst node, lane = column.
// out = relu( (Σ_s H[s]*dinv[s] + H[d]*dd) * dd + b )  -- dd factored out.
// Edges in batches of 8: 8 independent H-row loads in flight, then 8 FMAs.
// ---------------------------------------------------------------------------
__global__ __launch_bounds__(256) void agg_csr(const float* __restrict__ H,
                                               const float* __restrict__ dinv,
                                               const float* __restrict__ b,
                                               const int* __restrict__ off,
                                               const int* __restrict__ csr_src,
                                               float* __restrict__ out) {
    int wid  = (blockIdx.x * 256 + threadIdx.x) >> 6;
    int lane = threadIdx.x & 63;
    if (wid >= N_NODES) return;
    float dd = dinv[wid];
    float acc = H[(size_t)wid * 64 + lane] * dd;   // self term (scaled by dd at end)
    int beg = off[wid], end = off[wid + 1];
    for (int k0 = beg; k0 < end; k0 += 64) {
        int myk = k0 + lane;
        int   s_l  = (myk < end) ? csr_src[myk] : 0;
        float ds_l = (myk < end) ? dinv[s_l] : 0.f;
        int cnt = min(64, end - k0);
        int i = 0;
        for (; i + 8 <= cnt; i += 8) {
            float v[8], nm[8];
#pragma unroll
            for (int jj = 0; jj < 8; ++jj) {
                int s  = __shfl(s_l, i + jj);
                nm[jj] = __shfl(ds_l, i + jj);
                v[jj]  = H[(size_t)s * 64 + lane];
            }
#pragma unroll
            for (int jj = 0; jj < 8; ++jj) acc = fmaf(v[jj], nm[jj], acc);
        }
        for (; i < cnt; ++i) {
            int   s  = __shfl(s_l, i);
            float nm = __shfl(ds_l, i);
            acc = fmaf(H[(size_t)s * 64 + lane], nm, acc);
        }
    }
    out[(size_t)wid * 64 + lane] = fmaxf(fmaf(acc, dd, b[lane]), 0.f);
}

extern "C" void kernel_launch(void* const* d_in, const int* in_sizes, int n_in,
                              void* d_out, int out_size, void* d_ws, size_t ws_size,
                              hipStream_t stream) {
    const float* feat = (const float*)d_in[0];
    const float* W1   = (const float*)d_in[1];
    const float* b1   = (const float*)d_in[2];
    const float* W2   = (const float*)d_in[3];
    const float* b2   = (const float*)d_in[4];
    const void*  edges = d_in[5];
    float* out = (float*)d_out;

    char* ws = (char*)d_ws;
    const size_t SZ_N = 200704;  // >= 50001 ints
    int*   partial = (int*)ws;                        // 64 ints
    int*   cnt     = (int*)(ws + 1024);               // memset target
    float* dinv    = (float*)(ws + 1024 + SZ_N);
    int*   off     = (int*)(ws + 1024 + 2 * SZ_N);    // 50001 ints
    int*   cursor  = (int*)(ws + 1024 + 3 * SZ_N);
    int*   csr_src = (int*)(ws + 1024 + 4 * SZ_N);                 // 3.2 MB
    float* H       = (float*)(ws + 1024 + 4 * SZ_N + (size_t)N_EDGES * 4);  // 12.8 MB

    const int NB_E = (N_EDGES + 255) / 256;
    const int NB_G = (N_NODES + 63) / 64;
    const int NB_W = (N_NODES * 64 + 255) / 256;

    hipMemsetAsync(cnt, 0, SZ_N, stream);
    deg_count<<<NB_E, 256, 0, stream>>>(edges, cnt);
    scan_local<<<NCH, 1024, 0, stream>>>(cnt, off, partial, dinv);
    scan_mid<<<1, 64, 0, stream>>>(partial);
    scan_add<<<NCH, 1024, 0, stream>>>(off, partial, cursor);
    scatter_kernel<<<NB_E, 256, 0, stream>>>(edges, cursor, csr_src);

    // Layer 1
    gemm_kernel<IN_DIM><<<NB_G, 128, 0, stream>>>(feat, W1, H);
    agg_csr<<<NB_W, 256, 0, stream>>>(H, dinv, b1, off, csr_src, out);

    // Layer 2 (out holds relu'd z1)
    gemm_kernel<OUT_DIM><<<NB_G, 128, 0, stream>>>(out, W2, H);
    agg_csr<<<NB_W, 256, 0, stream>>>(H, dinv, b2, off, csr_src, out);
}